// Round 1
// baseline (5517.394 us; speedup 1.0000x reference)
//
#include <hip/hip_runtime.h>
#include <math.h>

// Problem constants
#define BATCH   8
#define LLAT    1024      // latent rows per batch
#define LTOK    2048      // token rows per batch after conv (10240/5)
#define DIM     512
#define TOKDIM  256
#define SRAW    10240
#define KCONV   1280      // 5*256 contiguous receptive field
#define SCALEF  0.044194173824159216f   // 1/sqrt(512)

// ---- bf16 helpers (bit-level, no lib dependency) ----
static __device__ __forceinline__ float bflo(unsigned int u) {
    union { unsigned int i; float f; } v; v.i = u << 16; return v.f;
}
static __device__ __forceinline__ float bfhi(unsigned int u) {
    union { unsigned int i; float f; } v; v.i = u & 0xffff0000u; return v.f;
}
static __device__ __forceinline__ unsigned short f2bf(float f) {
    union { float f; unsigned int i; } v; v.f = f;
    return (unsigned short)((v.i + 0x7fffu + ((v.i >> 16) & 1u)) >> 16);
}

// ---- pack conv weight: wp[e][k*256+c] = conv_w[e][c][k] ----
__global__ __launch_bounds__(256) void pack_convw(const float* __restrict__ cw,
                                                  float* __restrict__ wp) {
    int idx = blockIdx.x * 256 + threadIdx.x;          // < 512*1280
    int e = idx / KCONV, kk = idx % KCONV;
    int k = kk >> 8, c = kk & 255;
    wp[idx] = cw[e * KCONV + c * 5 + k];
}

// ---- generic NT GEMM: C[m,n] = dot(Arow(m), Bw[n,:K]) (+bias) ----
// AMODE 0: A row m at A + m*K (contiguous). AMODE 1: conv addressing into tokens.
// OUTBF 0: f32 out. 1: bf16 out.
template<int AMODE, int OUTBF>
__global__ __launch_bounds__(256) void gemm_nt(
    const float* __restrict__ A, const float* __restrict__ Bw,
    const float* __restrict__ bias, void* __restrict__ Cv,
    int M, int N, int K)
{
    __shared__ float As[64][17];
    __shared__ float Bs[64][17];
    int t = threadIdx.x, tx = t & 15, ty = t >> 4;
    int m0 = blockIdx.y << 6, n0 = blockIdx.x << 6;
    float acc[4][4] = {};
    for (int kt = 0; kt < K; kt += 16) {
        __syncthreads();
        #pragma unroll
        for (int q = 0; q < 4; ++q) {
            int e = t + (q << 8);
            int r = e >> 4, c = e & 15;
            int m = m0 + r;
            long ab;
            if (AMODE == 0) ab = (long)m * K;
            else            ab = (long)(m >> 11) * (SRAW * TOKDIM) + (long)(m & 2047) * KCONV;
            As[r][c] = A[ab + kt + c];
            Bs[r][c] = Bw[(long)(n0 + r) * K + kt + c];
        }
        __syncthreads();
        #pragma unroll
        for (int kc = 0; kc < 16; ++kc) {
            float ra[4], rb[4];
            #pragma unroll
            for (int x = 0; x < 4; ++x) ra[x] = As[(ty << 2) + x][kc];
            #pragma unroll
            for (int x = 0; x < 4; ++x) rb[x] = Bs[(tx << 2) + x][kc];
            #pragma unroll
            for (int x = 0; x < 4; ++x)
                #pragma unroll
                for (int y = 0; y < 4; ++y)
                    acc[x][y] += ra[x] * rb[y];
        }
    }
    #pragma unroll
    for (int x = 0; x < 4; ++x) {
        int m = m0 + (ty << 2) + x;
        int n = n0 + (tx << 2);
        float v0 = acc[x][0], v1 = acc[x][1], v2 = acc[x][2], v3 = acc[x][3];
        if (bias) { v0 += bias[n]; v1 += bias[n+1]; v2 += bias[n+2]; v3 += bias[n+3]; }
        if (OUTBF) {
            ushort4 u; u.x = f2bf(v0); u.y = f2bf(v1); u.z = f2bf(v2); u.w = f2bf(v3);
            *(ushort4*)((unsigned short*)Cv + (long)m * N + n) = u;
        } else {
            float4 f4; f4.x = v0; f4.y = v1; f4.z = v2; f4.w = v3;
            *(float4*)((float*)Cv + (long)m * N + n) = f4;
        }
    }
}

// ---- softmax stats over "rows" of A' where A'[q,k] = SCALE*dot(Rq[q], Rk[k]) ----
// Called twice: (Rlat,Rtok,Lq=1024,Lk=2048) for row-softmax stats,
//               (Rtok,Rlat,Lq=2048,Lk=1024) for col-softmax stats.
__global__ __launch_bounds__(256) void stats_pass(
    const unsigned short* __restrict__ Rq, const unsigned short* __restrict__ Rk,
    float* __restrict__ omax, float* __restrict__ osum, int Lq_, int Lk_)
{
    __shared__ unsigned short Qs[16][514];
    __shared__ unsigned short Ks[16][514];
    int t = threadIdx.x, b = blockIdx.y, q0 = blockIdx.x << 4;
    const unsigned short* Rqb = Rq + ((long)b * Lq_ + q0) * DIM;
    #pragma unroll
    for (int it = 0; it < 16; ++it) {
        int idx = t + (it << 8);
        int r = idx >> 8, cu = idx & 255;
        *(unsigned int*)&Qs[r][cu * 2] = *(const unsigned int*)&Rqb[(long)r * DIM + cu * 2];
    }
    int i = t >> 4, l16 = t & 15;
    float m_run = -INFINITY, s_run = 0.f;
    for (int c0 = 0; c0 < Lk_; c0 += 16) {
        __syncthreads();
        const unsigned short* Rkb = Rk + ((long)b * Lk_ + c0) * DIM;
        #pragma unroll
        for (int it = 0; it < 16; ++it) {
            int idx = t + (it << 8);
            int r = idx >> 8, cu = idx & 255;
            *(unsigned int*)&Ks[r][cu * 2] = *(const unsigned int*)&Rkb[(long)r * DIM + cu * 2];
        }
        __syncthreads();
        const unsigned int* qrow = (const unsigned int*)&Qs[i][0];
        const unsigned int* krow = (const unsigned int*)&Ks[l16][0];
        float s = 0.f;
        #pragma unroll 8
        for (int k2 = 0; k2 < 256; ++k2) {
            unsigned int a = qrow[k2], bb = krow[k2];
            s += bflo(a) * bflo(bb) + bfhi(a) * bfhi(bb);
        }
        float v = s * SCALEF;
        float cm = v;
        #pragma unroll
        for (int msk = 1; msk < 16; msk <<= 1) cm = fmaxf(cm, __shfl_xor(cm, msk));
        float nm = fmaxf(m_run, cm);
        float p = __expf(v - nm);
        #pragma unroll
        for (int msk = 1; msk < 16; msk <<= 1) p += __shfl_xor(p, msk);
        s_run = s_run * __expf(m_run - nm) + p;
        m_run = nm;
    }
    if (l16 == 0) {
        omax[(long)b * Lq_ + q0 + i] = m_run;
        osum[(long)b * Lq_ + q0 + i] = s_run;
    }
}

// ---- attention pass: out = base + softmax(scores) @ V, written to 2 places ----
__global__ __launch_bounds__(256) void attn_pass(
    const unsigned short* __restrict__ Rq, const unsigned short* __restrict__ Rk,
    const unsigned short* __restrict__ V,
    const float* __restrict__ qmax, const float* __restrict__ qsum,
    const float* __restrict__ base,
    float* __restrict__ out1, float* __restrict__ out2,
    int Lq_, int Lk_, int catbase)
{
    __shared__ unsigned short Qs[16][514];
    __shared__ unsigned short Ks[16][514];
    __shared__ unsigned short Vs[16][514];
    __shared__ float Ps[16][17];
    int t = threadIdx.x, b = blockIdx.y, q0 = blockIdx.x << 4;
    const unsigned short* Rqb = Rq + ((long)b * Lq_ + q0) * DIM;
    #pragma unroll
    for (int it = 0; it < 16; ++it) {
        int idx = t + (it << 8);
        int r = idx >> 8, cu = idx & 255;
        *(unsigned int*)&Qs[r][cu * 2] = *(const unsigned int*)&Rqb[(long)r * DIM + cu * 2];
    }
    int i = t >> 4, l16 = t & 15;
    float qm = qmax[(long)b * Lq_ + q0 + i];
    float inv = 1.f / qsum[(long)b * Lq_ + q0 + i];
    float acc[32] = {};
    for (int c0 = 0; c0 < Lk_; c0 += 16) {
        __syncthreads();
        const unsigned short* Rkb = Rk + ((long)b * Lk_ + c0) * DIM;
        const unsigned short* Vb  = V  + ((long)b * Lk_ + c0) * DIM;
        #pragma unroll
        for (int it = 0; it < 16; ++it) {
            int idx = t + (it << 8);
            int r = idx >> 8, cu = idx & 255;
            *(unsigned int*)&Ks[r][cu * 2] = *(const unsigned int*)&Rkb[(long)r * DIM + cu * 2];
            *(unsigned int*)&Vs[r][cu * 2] = *(const unsigned int*)&Vb [(long)r * DIM + cu * 2];
        }
        __syncthreads();
        // GEMM1: one score per thread
        {
            const unsigned int* qrow = (const unsigned int*)&Qs[i][0];
            const unsigned int* krow = (const unsigned int*)&Ks[l16][0];
            float s = 0.f;
            #pragma unroll 8
            for (int k2 = 0; k2 < 256; ++k2) {
                unsigned int a = qrow[k2], bb = krow[k2];
                s += bflo(a) * bflo(bb) + bfhi(a) * bfhi(bb);
            }
            Ps[i][l16] = __expf(s * SCALEF - qm);
        }
        __syncthreads();
        // GEMM2: acc[row i, cols l16*2 + jj*32 (+1)] += P @ V
        #pragma unroll 4
        for (int kk = 0; kk < 16; ++kk) {
            float p = Ps[i][kk];
            const unsigned int* vr = (const unsigned int*)&Vs[kk][0];
            #pragma unroll
            for (int jj = 0; jj < 16; ++jj) {
                unsigned int vv = vr[l16 + (jj << 4)];
                acc[2 * jj]     += p * bflo(vv);
                acc[2 * jj + 1] += p * bfhi(vv);
            }
        }
    }
    long rowq = (long)b * Lq_ + q0 + i;
    const float* bb = base + rowq * DIM;
    float* o1 = out1 + rowq * DIM;
    float* o2 = out2 + ((long)b * 3072 + catbase + q0 + i) * DIM;
    #pragma unroll
    for (int jj = 0; jj < 16; ++jj) {
        int c = l16 * 2 + jj * 32;
        float v0 = bb[c]     + acc[2 * jj]     * inv;
        float v1 = bb[c + 1] + acc[2 * jj + 1] * inv;
        o1[c] = v0; o1[c + 1] = v1;
        o2[c] = v0; o2[c + 1] = v1;
    }
}

extern "C" void kernel_launch(void* const* d_in, const int* in_sizes, int n_in,
                              void* d_out, int out_size, void* d_ws, size_t ws_size,
                              hipStream_t stream)
{
    const float* latents = (const float*)d_in[0];
    const float* tokens  = (const float*)d_in[1];
    const float* W_lat   = (const float*)d_in[2];
    const float* W_tok   = (const float*)d_in[3];
    const float* W_vlat  = (const float*)d_in[4];
    const float* W_vtok  = (const float*)d_in[5];
    const float* conv_w  = (const float*)d_in[6];
    const float* conv_b  = (const float*)d_in[7];
    float* out = (float*)d_out;
    char* ws = (char*)d_ws;

    // workspace layout (bytes)
    float*          tok  = (float*)(ws + 0);                  // 8*2048*512*4   = 33,554,432
    float*          wp   = (float*)(ws + 33554432);           // 512*1280*4     =  2,621,440
    unsigned short* rlat = (unsigned short*)(ws + 36175872);  // 8*1024*512*2   =  8,388,608
    unsigned short* vlat = (unsigned short*)(ws + 44564480);  //                   8,388,608
    unsigned short* rtok = (unsigned short*)(ws + 52953088);  // 8*2048*512*2   = 16,777,216
    unsigned short* vtok = (unsigned short*)(ws + 69730304);  //                  16,777,216
    float*          rmax = (float*)(ws + 86507520);           // 8*1024*4
    float*          rsum = (float*)(ws + 86540288);
    float*          cmax = (float*)(ws + 86573056);           // 8*2048*4
    float*          csum = (float*)(ws + 86638592);           // total ~86.7 MB

    // 1) pack conv weight, conv-as-GEMM -> tok (f32)
    pack_convw<<<dim3(2560), dim3(256), 0, stream>>>(conv_w, wp);
    gemm_nt<1, 0><<<dim3(8, 256), 256, 0, stream>>>(tokens, wp, conv_b, tok, 16384, 512, 1280);

    // 2) four projections -> bf16
    gemm_nt<0, 1><<<dim3(8, 128), 256, 0, stream>>>(latents, W_lat,  nullptr, rlat, 8192, 512, 512);
    gemm_nt<0, 1><<<dim3(8, 128), 256, 0, stream>>>(latents, W_vlat, nullptr, vlat, 8192, 512, 512);
    gemm_nt<0, 1><<<dim3(8, 256), 256, 0, stream>>>(tok, W_tok,  nullptr, rtok, 16384, 512, 512);
    gemm_nt<0, 1><<<dim3(8, 256), 256, 0, stream>>>(tok, W_vtok, nullptr, vtok, 16384, 512, 512);

    // 3) softmax stats: rows (over s) and cols (over l)
    stats_pass<<<dim3(64, 8),  256, 0, stream>>>(rlat, rtok, rmax, rsum, 1024, 2048);
    stats_pass<<<dim3(128, 8), 256, 0, stream>>>(rtok, rlat, cmax, csum, 2048, 1024);

    // 4) delta passes, fused residual add, each written to its own region + concat region
    attn_pass<<<dim3(64, 8),  256, 0, stream>>>(rlat, rtok, vtok, rmax, rsum, latents,
                                                out, out + 12582912, 1024, 2048, 0);
    attn_pass<<<dim3(128, 8), 256, 0, stream>>>(rtok, rlat, vlat, cmax, csum, tok,
                                                out + 4194304, out + 12582912, 2048, 1024, 1024);
}

// Round 2
// 340.617 us; speedup vs baseline: 16.1982x; 16.1982x over previous
//
#include <hip/hip_runtime.h>
#include <math.h>

#define SCALEF 0.044194173824159216f   // 1/sqrt(512)

typedef __attribute__((ext_vector_type(8))) short bf16x8;
typedef __attribute__((ext_vector_type(4))) float f32x4;

static __device__ __forceinline__ unsigned short f2bf(float f) {
    union { float f; unsigned int i; } v; v.f = f;
    return (unsigned short)((v.i + 0x7fffu + ((v.i >> 16) & 1u)) >> 16);
}
static __device__ __forceinline__ float bf2f(unsigned short h) {
    union { unsigned int i; float f; } v; v.i = ((unsigned int)h) << 16;
    return v.f;
}
static __device__ __forceinline__ void gload16(const void* g, void* l) {
    __builtin_amdgcn_global_load_lds(
        (const __attribute__((address_space(1))) unsigned int*)g,
        (__attribute__((address_space(3))) unsigned int*)l, 16, 0, 0);
}

// ---------------- converters ----------------
__global__ __launch_bounds__(256) void cvt_bf16(const float4* __restrict__ s,
                                                ushort4* __restrict__ d, long n4) {
    for (long i = blockIdx.x * 256L + threadIdx.x; i < n4; i += gridDim.x * 256L) {
        float4 f = s[i];
        ushort4 u; u.x = f2bf(f.x); u.y = f2bf(f.y); u.z = f2bf(f.z); u.w = f2bf(f.w);
        d[i] = u;
    }
}

// wp[e][k*256+c] = conv_w[e][c][k], bf16
__global__ __launch_bounds__(256) void pack_convw_bf(const float* __restrict__ cw,
                                                     unsigned short* __restrict__ wp) {
    int idx = blockIdx.x * 256 + threadIdx.x;   // < 512*1280
    int e = idx / 1280, kk = idx % 1280;
    int k = kk >> 8, c = kk & 255;
    wp[idx] = f2bf(cw[e * 1280 + c * 5 + k]);
}

// ---------------- in-place row softmax (bf16), 1/sum folded in ----------------
template<int RL>
__global__ __launch_bounds__(256) void rowsoftmax(unsigned short* __restrict__ S) {
    constexpr int U = RL / 512;                 // u32 words per thread
    long row = blockIdx.x;
    unsigned int* p = (unsigned int*)(S + row * (long)RL);
    const int t = threadIdx.x, lane = t & 63, wid = t >> 6;
    unsigned int u[U];
    float v[2 * U];
    #pragma unroll
    for (int i = 0; i < U; ++i) u[i] = p[t + (i << 8)];
    #pragma unroll
    for (int i = 0; i < U; ++i) {
        v[2 * i]     = bf2f((unsigned short)(u[i] & 0xffffu));
        v[2 * i + 1] = bf2f((unsigned short)(u[i] >> 16));
    }
    float m = -INFINITY;
    #pragma unroll
    for (int i = 0; i < 2 * U; ++i) m = fmaxf(m, v[i]);
    #pragma unroll
    for (int k = 1; k < 64; k <<= 1) m = fmaxf(m, __shfl_xor(m, k));
    __shared__ float redm[4], reds[4];
    if (lane == 0) redm[wid] = m;
    __syncthreads();
    m = fmaxf(fmaxf(redm[0], redm[1]), fmaxf(redm[2], redm[3]));
    float s = 0.f, e[2 * U];
    #pragma unroll
    for (int i = 0; i < 2 * U; ++i) { e[i] = __expf(v[i] - m); s += e[i]; }
    #pragma unroll
    for (int k = 1; k < 64; k <<= 1) s += __shfl_xor(s, k);
    if (lane == 0) reds[wid] = s;
    __syncthreads();
    s = reds[0] + reds[1] + reds[2] + reds[3];
    float inv = 1.f / s;
    #pragma unroll
    for (int i = 0; i < U; ++i) {
        unsigned int lo = f2bf(e[2 * i] * inv);
        unsigned int hi = f2bf(e[2 * i + 1] * inv);
        p[t + (i << 8)] = lo | (hi << 16);
    }
}

// ---------------- MFMA NT GEMM: C[m,n] = sum_k A[m,k] * B[n,k] ----------------
// 128x128 tile, BK=32, 4 waves (2x2 of 64x64), 16x16x32 bf16 MFMA.
// global_load_lds staging, 16B-granule XOR swizzle applied on the GLOBAL source
// (dest stays linear) and undone on the ds_read side: cphys = clog ^ ((row>>1)&3).
// AMODE: 0 = row m at A + m*lda.  1 = conv addressing into raw tokens (bf16).
// EPI:   0 = bf16 out (Cb) * scale
//        1 = +bias(f32, basep) then bf16 out (Cb)
//        2 = f32 base (basep) + acc -> C0 and C1
//        3 = bf16 base (basep) + acc -> C0 and C1
template<int AMODE, int EPI>
__global__ __launch_bounds__(256) void mm_nt(
    const unsigned short* __restrict__ A, const unsigned short* __restrict__ B,
    long bsA, long bsB, int lda, int ldb, int K,
    unsigned short* __restrict__ Cb, long bsCb,
    float* __restrict__ C0, long bsC0, float* __restrict__ C1, long bsC1,
    const void* __restrict__ basep, long bsBase, int ldc, float scale)
{
    __shared__ unsigned short sm[8192];         // A: 8KB, B: 8KB
    const int t = threadIdx.x, lane = t & 63, wid = t >> 6;
    const int z = blockIdx.z;
    const int m0 = blockIdx.y << 7, n0 = blockIdx.x << 7;
    const unsigned short* Ab = A + (long)z * bsA;
    const unsigned short* Bb = B + (long)z * bsB;

    // staging: chunk ci covers tile rows [ci*16, ci*16+16); 4 lanes per 64B row
    const int rA0 = wid * 16 + (lane >> 2);
    const int rA1 = rA0 + 64;
    const int cs0 = (lane & 3) ^ ((rA0 >> 1) & 3);
    const int cs1 = (lane & 3) ^ ((rA1 >> 1) & 3);

    long aoff0, aoff1;
    if (AMODE == 0) {
        aoff0 = (long)(m0 + rA0) * lda + cs0 * 8;
        aoff1 = (long)(m0 + rA1) * lda + cs1 * 8;
    } else {
        int ma = m0 + rA0, mb = m0 + rA1;
        aoff0 = (long)(ma >> 11) * 2621440 + (long)(ma & 2047) * 1280 + cs0 * 8;
        aoff1 = (long)(mb >> 11) * 2621440 + (long)(mb & 2047) * 1280 + cs1 * 8;
    }
    const long boff0 = (long)(n0 + rA0) * ldb + cs0 * 8;
    const long boff1 = (long)(n0 + rA1) * ldb + cs1 * 8;

    char* smc = (char*)sm;
    char* dstA0 = smc + (wid << 10);
    char* dstA1 = smc + ((wid + 4) << 10);
    char* dstB0 = smc + 8192 + (wid << 10);
    char* dstB1 = smc + 8192 + ((wid + 4) << 10);

    const int wr = wid >> 1, wc = wid & 1;
    const int l15 = lane & 15, cslot = lane >> 4;
    int offA[4], offB[4];
    #pragma unroll
    for (int i = 0; i < 4; ++i) {
        int r = wr * 64 + i * 16 + l15;
        offA[i] = r * 64 + ((cslot ^ ((r >> 1) & 3)) << 4);
        int rb = wc * 64 + i * 16 + l15;
        offB[i] = 8192 + rb * 64 + ((cslot ^ ((rb >> 1) & 3)) << 4);
    }

    f32x4 acc[4][4];
    #pragma unroll
    for (int i = 0; i < 4; ++i)
        #pragma unroll
        for (int j = 0; j < 4; ++j)
            acc[i][j] = (f32x4)(0.f);

    for (int kt = 0; kt < K; kt += 32) {
        __syncthreads();
        gload16(Ab + aoff0 + kt, dstA0);
        gload16(Ab + aoff1 + kt, dstA1);
        gload16(Bb + boff0 + kt, dstB0);
        gload16(Bb + boff1 + kt, dstB1);
        __syncthreads();
        bf16x8 af[4], bfr[4];
        #pragma unroll
        for (int i = 0; i < 4; ++i) af[i]  = *(const bf16x8*)(smc + offA[i]);
        #pragma unroll
        for (int i = 0; i < 4; ++i) bfr[i] = *(const bf16x8*)(smc + offB[i]);
        #pragma unroll
        for (int i = 0; i < 4; ++i)
            #pragma unroll
            for (int j = 0; j < 4; ++j)
                acc[i][j] = __builtin_amdgcn_mfma_f32_16x16x32_bf16(af[i], bfr[j], acc[i][j], 0, 0, 0);
    }

    // epilogue: C/D frag layout col=lane&15, row=(lane>>4)*4+q  [m89-verified]
    const int colb = n0 + wc * 64 + l15;
    const int rowb = m0 + wr * 64 + cslot * 4;
    #pragma unroll
    for (int i = 0; i < 4; ++i) {
        #pragma unroll
        for (int j = 0; j < 4; ++j) {
            int n = colb + j * 16;
            #pragma unroll
            for (int q = 0; q < 4; ++q) {
                int m = rowb + i * 16 + q;
                float v = acc[i][j][q];
                if (EPI == 0) {
                    Cb[(long)z * bsCb + (long)m * ldc + n] = f2bf(v * scale);
                } else if (EPI == 1) {
                    v += ((const float*)basep)[n];
                    Cb[(long)m * ldc + n] = f2bf(v);
                } else if (EPI == 2) {
                    float bv = ((const float*)basep)[(long)z * bsBase + (long)m * ldc + n];
                    float o = bv + v;
                    C0[(long)z * bsC0 + (long)m * ldc + n] = o;
                    C1[(long)z * bsC1 + (long)m * ldc + n] = o;
                } else {
                    float bv = bf2f(((const unsigned short*)basep)[(long)z * bsBase + (long)m * ldc + n]);
                    float o = bv + v;
                    C0[(long)z * bsC0 + (long)m * ldc + n] = o;
                    C1[(long)z * bsC1 + (long)m * ldc + n] = o;
                }
            }
        }
    }
}

extern "C" void kernel_launch(void* const* d_in, const int* in_sizes, int n_in,
                              void* d_out, int out_size, void* d_ws, size_t ws_size,
                              hipStream_t stream)
{
    const float* latents = (const float*)d_in[0];
    const float* tokens  = (const float*)d_in[1];
    const float* W_lat   = (const float*)d_in[2];
    const float* W_tok   = (const float*)d_in[3];
    const float* W_vlat  = (const float*)d_in[4];
    const float* W_vtok  = (const float*)d_in[5];
    const float* conv_w  = (const float*)d_in[6];
    const float* conv_b  = (const float*)d_in[7];
    float* out = (float*)d_out;
    char* ws = (char*)d_ws;

    // workspace layout (bytes)
    unsigned short* S    = (unsigned short*)(ws);              // 8x1024x2048 bf16 = 33,554,432
    unsigned short* ST   = (unsigned short*)(ws + 33554432);   // 8x2048x1024 bf16
    unsigned short* tokb = (unsigned short*)(ws + 67108864);   // 8x2048x512  bf16 = 16,777,216
    unsigned short* latb = (unsigned short*)(ws + 83886080);   // 8x1024x512  bf16 =  8,388,608
    unsigned short* rlat = (unsigned short*)(ws + 92274688);   //  8,388,608
    unsigned short* rtok = (unsigned short*)(ws + 100663296);  // 16,777,216
    unsigned short* vlT  = (unsigned short*)(ws + 117440512);  // 8x512x1024 =  8,388,608
    unsigned short* vtT  = (unsigned short*)(ws + 125829120);  // 8x512x2048 = 16,777,216
    unsigned short* wpb  = (unsigned short*)(ws + 142606336);  // 512x1280   =  1,310,720
    unsigned short* wlb  = (unsigned short*)(ws + 143917056);  // 512x512 x4 =  2,097,152
    unsigned short* wtb  = (unsigned short*)(ws + 144441344);
    unsigned short* wvlb = (unsigned short*)(ws + 144965632);
    unsigned short* wvtb = (unsigned short*)(ws + 145489920);  // end 146,014,208
    // tokens-as-bf16 scratch lives in the concat region of d_out (overwritten later)
    unsigned short* tknb = (unsigned short*)(out + 12582912);  // 41,943,040 B <= 50,331,648 B

    // 1) dtype conversions + conv weight pack
    cvt_bf16<<<2048, 256, 0, stream>>>((const float4*)tokens,  (ushort4*)tknb, 5242880);
    cvt_bf16<<<2048, 256, 0, stream>>>((const float4*)latents, (ushort4*)latb, 1048576);
    cvt_bf16<<<256, 256, 0, stream>>>((const float4*)W_lat,  (ushort4*)wlb,  65536);
    cvt_bf16<<<256, 256, 0, stream>>>((const float4*)W_tok,  (ushort4*)wtb,  65536);
    cvt_bf16<<<256, 256, 0, stream>>>((const float4*)W_vlat, (ushort4*)wvlb, 65536);
    cvt_bf16<<<256, 256, 0, stream>>>((const float4*)W_vtok, (ushort4*)wvtb, 65536);
    pack_convw_bf<<<2560, 256, 0, stream>>>(conv_w, wpb);

    // 2) conv-as-GEMM: tok_bf[m=16384][512], +bias
    mm_nt<1, 1><<<dim3(4, 128, 1), 256, 0, stream>>>(
        tknb, wpb, 0, 0, 1280, 1280, 1280,
        tokb, 0, nullptr, 0, nullptr, 0, conv_b, 0, 512, 1.f);

    // 3) projections (batches folded into M)
    mm_nt<0, 0><<<dim3(4, 64, 1), 256, 0, stream>>>(
        latb, wlb, 0, 0, 512, 512, 512, rlat, 0, nullptr, 0, nullptr, 0, nullptr, 0, 512, 1.f);
    mm_nt<0, 0><<<dim3(4, 128, 1), 256, 0, stream>>>(
        tokb, wtb, 0, 0, 512, 512, 512, rtok, 0, nullptr, 0, nullptr, 0, nullptr, 0, 512, 1.f);
    // V projections computed transposed: VT[e, l] = sum_d W[e,d] X[l,d]
    mm_nt<0, 0><<<dim3(8, 4, 8), 256, 0, stream>>>(
        wvlb, latb, 0, 524288, 512, 512, 512, vlT, 524288, nullptr, 0, nullptr, 0, nullptr, 0, 1024, 1.f);
    mm_nt<0, 0><<<dim3(16, 4, 8), 256, 0, stream>>>(
        wvtb, tokb, 0, 1048576, 512, 512, 512, vtT, 1048576, nullptr, 0, nullptr, 0, nullptr, 0, 2048, 1.f);

    // 4) score matrices S = scale * Rlat Rtok^T  and its transpose
    mm_nt<0, 0><<<dim3(16, 8, 8), 256, 0, stream>>>(
        rlat, rtok, 524288, 1048576, 512, 512, 512, S, 2097152, nullptr, 0, nullptr, 0, nullptr, 0, 2048, SCALEF);
    mm_nt<0, 0><<<dim3(8, 16, 8), 256, 0, stream>>>(
        rtok, rlat, 1048576, 524288, 512, 512, 512, ST, 2097152, nullptr, 0, nullptr, 0, nullptr, 0, 1024, SCALEF);

    // 5) softmax in place (row-wise on S; row-wise on ST == column-wise on S)
    rowsoftmax<2048><<<8192, 256, 0, stream>>>(S);
    rowsoftmax<1024><<<16384, 256, 0, stream>>>(ST);

    // 6) delta GEMMs with fused residual + dual write (own region + concat region)
    mm_nt<0, 2><<<dim3(4, 8, 8), 256, 0, stream>>>(
        S, vtT, 2097152, 1048576, 2048, 2048, 2048,
        nullptr, 0, out, 524288, out + 12582912, 1572864, latents, 524288, 512, 1.f);
    mm_nt<0, 3><<<dim3(4, 16, 8), 256, 0, stream>>>(
        ST, vlT, 2097152, 524288, 1024, 1024, 1024,
        nullptr, 0, out + 4194304, 1048576, out + 12582912 + 524288, 1572864, tokb, 1048576, 512, 1.f);
}

// Round 3
// 281.721 us; speedup vs baseline: 19.5846x; 1.2091x over previous
//
#include <hip/hip_runtime.h>
#include <math.h>

#define SCALEF 0.044194173824159216f   // 1/sqrt(512)

typedef __attribute__((ext_vector_type(8))) short bf16x8;
typedef __attribute__((ext_vector_type(4))) float f32x4;

static __device__ __forceinline__ unsigned short f2bf(float f) {
    union { float f; unsigned int i; } v; v.f = f;
    return (unsigned short)((v.i + 0x7fffu + ((v.i >> 16) & 1u)) >> 16);
}
static __device__ __forceinline__ float bf2f(unsigned short h) {
    union { unsigned int i; float f; } v; v.i = ((unsigned int)h) << 16;
    return v.f;
}
static __device__ __forceinline__ void gload16(const void* g, void* l) {
    __builtin_amdgcn_global_load_lds(
        (const __attribute__((address_space(1))) unsigned int*)g,
        (__attribute__((address_space(3))) unsigned int*)l, 16, 0, 0);
}

// ---------------- one-shot prep: all dtype conversions + conv weight pack ----
// unit layout (grid-stride over 6,881,280 units):
//   [0, 5242880)            tokens  f32x4 -> bf16x4   (tknb)
//   [.., +1048576)          latents f32x4 -> bf16x4   (latb)
//   [.., +65536) x4         W_lat/W_tok/W_vlat/W_vtok (wlb/wtb/wvlb/wvtb)
//   [.., +327680)           conv pack u32: wp[e][k*128+c2] = {cw[e][2c2][k], cw[e][2c2+1][k]}
__global__ __launch_bounds__(256) void prep_all(
    const float4* __restrict__ tokens, const float4* __restrict__ latents,
    const float4* __restrict__ wl, const float4* __restrict__ wt,
    const float4* __restrict__ wvl, const float4* __restrict__ wvt,
    const float* __restrict__ cw,
    ushort4* __restrict__ tknb, ushort4* __restrict__ latb,
    ushort4* __restrict__ wlb, ushort4* __restrict__ wtb,
    ushort4* __restrict__ wvlb, ushort4* __restrict__ wvtb,
    unsigned int* __restrict__ wpb)
{
    const long NTOK = 5242880, NLAT = 1048576, NW = 65536, NCV = 327680;
    for (long i = blockIdx.x * 256L + threadIdx.x; i < NTOK + NLAT + 4 * NW + NCV;
         i += gridDim.x * 256L) {
        long r = i;
        const float4* s = nullptr; ushort4* d = nullptr; long o = 0;
        if (r < NTOK) { s = tokens; d = tknb; o = r; }
        else if ((r -= NTOK) < NLAT) { s = latents; d = latb; o = r; }
        else if ((r -= NLAT) < NW) { s = wl; d = wlb; o = r; }
        else if ((r -= NW) < NW) { s = wt; d = wtb; o = r; }
        else if ((r -= NW) < NW) { s = wvl; d = wvlb; o = r; }
        else if ((r -= NW) < NW) { s = wvt; d = wvtb; o = r; }
        else {
            r -= NW;  // conv unit
            long e = r / 640, rr = r % 640, k = rr >> 7, c2 = rr & 127;
            unsigned int lo = f2bf(cw[e * 1280 + (2 * c2) * 5 + k]);
            unsigned int hi = f2bf(cw[e * 1280 + (2 * c2 + 1) * 5 + k]);
            wpb[r] = lo | (hi << 16);
            continue;
        }
        float4 f = s[o];
        ushort4 u; u.x = f2bf(f.x); u.y = f2bf(f.y); u.z = f2bf(f.z); u.w = f2bf(f.w);
        d[o] = u;
    }
}

// ---------------- in-place row softmax (bf16), 1/sum folded in ----------------
template<int RL>
__global__ __launch_bounds__(256) void rowsoftmax(unsigned short* __restrict__ S) {
    constexpr int U = RL / 512;                 // u32 words per thread
    long row = blockIdx.x;
    unsigned int* p = (unsigned int*)(S + row * (long)RL);
    const int t = threadIdx.x, lane = t & 63, wid = t >> 6;
    unsigned int u[U];
    float v[2 * U];
    #pragma unroll
    for (int i = 0; i < U; ++i) u[i] = p[t + (i << 8)];
    #pragma unroll
    for (int i = 0; i < U; ++i) {
        v[2 * i]     = bf2f((unsigned short)(u[i] & 0xffffu));
        v[2 * i + 1] = bf2f((unsigned short)(u[i] >> 16));
    }
    float m = -INFINITY;
    #pragma unroll
    for (int i = 0; i < 2 * U; ++i) m = fmaxf(m, v[i]);
    #pragma unroll
    for (int k = 1; k < 64; k <<= 1) m = fmaxf(m, __shfl_xor(m, k));
    __shared__ float redm[4], reds[4];
    if (lane == 0) redm[wid] = m;
    __syncthreads();
    m = fmaxf(fmaxf(redm[0], redm[1]), fmaxf(redm[2], redm[3]));
    float s = 0.f, e[2 * U];
    #pragma unroll
    for (int i = 0; i < 2 * U; ++i) { e[i] = __expf(v[i] - m); s += e[i]; }
    #pragma unroll
    for (int k = 1; k < 64; k <<= 1) s += __shfl_xor(s, k);
    if (lane == 0) reds[wid] = s;
    __syncthreads();
    s = reds[0] + reds[1] + reds[2] + reds[3];
    float inv = 1.f / s;
    #pragma unroll
    for (int i = 0; i < U; ++i) {
        unsigned int lo = f2bf(e[2 * i] * inv);
        unsigned int hi = f2bf(e[2 * i + 1] * inv);
        p[t + (i << 8)] = lo | (hi << 16);
    }
}

// ---------------- MFMA NT GEMM: C[m,n] = sum_k A[m,k] * B[n,k] ----------------
// 128x128 tile, BK=32, 4 waves (2x2 of 64x64), 16x16x32 bf16 MFMA.
// Double-buffered LDS (2 x 16KB) with prefetch: next tile's global_load_lds is
// issued BEFORE computing the current tile; counted s_waitcnt vmcnt(4) + raw
// s_barrier (never a full drain mid-loop).  16B-granule XOR swizzle applied on
// the GLOBAL source (dest stays linear) and undone on the ds_read side.
// AMODE: 0 = row m at A + m*lda.  1 = conv addressing into raw tokens (bf16).
// EPI:   0 = bf16 out (Cb) * scale
//        1 = +bias(f32, basep) then bf16 out (Cb)
//        2 = f32 base (basep) + acc -> C0 and C1
//        3 = bf16 base (basep) + acc -> C0 and C1
template<int AMODE, int EPI>
__global__ __launch_bounds__(256) void mm_nt(
    const unsigned short* __restrict__ A, const unsigned short* __restrict__ B,
    long bsA, long bsB, int lda, int ldb, int K,
    unsigned short* __restrict__ Cb, long bsCb,
    float* __restrict__ C0, long bsC0, float* __restrict__ C1, long bsC1,
    const void* __restrict__ basep, long bsBase, int ldc, float scale)
{
    __shared__ unsigned short sm[16384];        // 32KB: 2 bufs x (A 8KB + B 8KB)
    const int t = threadIdx.x, lane = t & 63, wid = t >> 6;
    const int z = blockIdx.z;
    const int m0 = blockIdx.y << 7, n0 = blockIdx.x << 7;
    const unsigned short* Ab = A + (long)z * bsA;
    const unsigned short* Bb = B + (long)z * bsB;

    // staging: wave wid covers tile rows [wid*16, wid*16+16) and +64; 4 lanes/64B row
    const int rA0 = wid * 16 + (lane >> 2);
    const int rA1 = rA0 + 64;
    const int cs0 = (lane & 3) ^ ((rA0 >> 1) & 3);
    const int cs1 = (lane & 3) ^ ((rA1 >> 1) & 3);

    long aoff0, aoff1;
    if (AMODE == 0) {
        aoff0 = (long)(m0 + rA0) * lda + cs0 * 8;
        aoff1 = (long)(m0 + rA1) * lda + cs1 * 8;
    } else {
        int ma = m0 + rA0, mb = m0 + rA1;
        aoff0 = (long)(ma >> 11) * 2621440 + (long)(ma & 2047) * 1280 + cs0 * 8;
        aoff1 = (long)(mb >> 11) * 2621440 + (long)(mb & 2047) * 1280 + cs1 * 8;
    }
    const long boff0 = (long)(n0 + rA0) * ldb + cs0 * 8;
    const long boff1 = (long)(n0 + rA1) * ldb + cs1 * 8;

    char* smc = (char*)sm;
    const int dA0 = (wid << 10), dA1 = ((wid + 4) << 10);
    const int dB0 = 8192 + (wid << 10), dB1 = 8192 + ((wid + 4) << 10);

    const int wr = wid >> 1, wc = wid & 1;
    const int l15 = lane & 15, cslot = lane >> 4;
    int offA[4], offB[4];
    #pragma unroll
    for (int i = 0; i < 4; ++i) {
        int r = wr * 64 + i * 16 + l15;
        offA[i] = r * 64 + ((cslot ^ ((r >> 1) & 3)) << 4);
        int rb = wc * 64 + i * 16 + l15;
        offB[i] = 8192 + rb * 64 + ((cslot ^ ((rb >> 1) & 3)) << 4);
    }

    f32x4 acc[4][4];
    #pragma unroll
    for (int i = 0; i < 4; ++i)
        #pragma unroll
        for (int j = 0; j < 4; ++j)
            acc[i][j] = (f32x4)(0.f);

#define STAGE(p, ktv) do {                                   \
        int kb_ = (ktv);                                     \
        int bo_ = (p) * 16384;                               \
        gload16(Ab + aoff0 + kb_, smc + bo_ + dA0);          \
        gload16(Ab + aoff1 + kb_, smc + bo_ + dA1);          \
        gload16(Bb + boff0 + kb_, smc + bo_ + dB0);          \
        gload16(Bb + boff1 + kb_, smc + bo_ + dB1);          \
    } while (0)

    const int nt = K >> 5;
    STAGE(0, 0);
    int cur = 0;
    for (int it = 0; it < nt; ++it) {
        if (it + 1 < nt) {
            STAGE(cur ^ 1, (it + 1) << 5);
            asm volatile("s_waitcnt vmcnt(4)" ::: "memory");
        } else {
            asm volatile("s_waitcnt vmcnt(0)" ::: "memory");
        }
        __builtin_amdgcn_s_barrier();
        const char* base = smc + cur * 16384;
        bf16x8 af[4], bfr[4];
        #pragma unroll
        for (int i = 0; i < 4; ++i) af[i]  = *(const bf16x8*)(base + offA[i]);
        #pragma unroll
        for (int i = 0; i < 4; ++i) bfr[i] = *(const bf16x8*)(base + offB[i]);
        #pragma unroll
        for (int i = 0; i < 4; ++i)
            #pragma unroll
            for (int j = 0; j < 4; ++j)
                acc[i][j] = __builtin_amdgcn_mfma_f32_16x16x32_bf16(af[i], bfr[j], acc[i][j], 0, 0, 0);
        asm volatile("s_waitcnt lgkmcnt(0)" ::: "memory");
        __builtin_amdgcn_s_barrier();
        cur ^= 1;
    }
#undef STAGE

    // epilogue: C/D frag layout col=lane&15, row=(lane>>4)*4+q  [m89-verified]
    const int colb = n0 + wc * 64 + l15;
    const int rowb = m0 + wr * 64 + cslot * 4;
    #pragma unroll
    for (int i = 0; i < 4; ++i) {
        #pragma unroll
        for (int j = 0; j < 4; ++j) {
            int n = colb + j * 16;
            #pragma unroll
            for (int q = 0; q < 4; ++q) {
                int m = rowb + i * 16 + q;
                float v = acc[i][j][q];
                if (EPI == 0) {
                    Cb[(long)z * bsCb + (long)m * ldc + n] = f2bf(v * scale);
                } else if (EPI == 1) {
                    v += ((const float*)basep)[n];
                    Cb[(long)m * ldc + n] = f2bf(v);
                } else if (EPI == 2) {
                    float bv = ((const float*)basep)[(long)z * bsBase + (long)m * ldc + n];
                    float o = bv + v;
                    C0[(long)z * bsC0 + (long)m * ldc + n] = o;
                    C1[(long)z * bsC1 + (long)m * ldc + n] = o;
                } else {
                    float bv = bf2f(((const unsigned short*)basep)[(long)z * bsBase + (long)m * ldc + n]);
                    float o = bv + v;
                    C0[(long)z * bsC0 + (long)m * ldc + n] = o;
                    C1[(long)z * bsC1 + (long)m * ldc + n] = o;
                }
            }
        }
    }
}

extern "C" void kernel_launch(void* const* d_in, const int* in_sizes, int n_in,
                              void* d_out, int out_size, void* d_ws, size_t ws_size,
                              hipStream_t stream)
{
    const float* latents = (const float*)d_in[0];
    const float* tokens  = (const float*)d_in[1];
    const float* W_lat   = (const float*)d_in[2];
    const float* W_tok   = (const float*)d_in[3];
    const float* W_vlat  = (const float*)d_in[4];
    const float* W_vtok  = (const float*)d_in[5];
    const float* conv_w  = (const float*)d_in[6];
    const float* conv_b  = (const float*)d_in[7];
    float* out = (float*)d_out;
    char* ws = (char*)d_ws;

    // workspace layout (bytes)
    unsigned short* S    = (unsigned short*)(ws);              // 8x1024x2048 bf16 = 33,554,432
    unsigned short* ST   = (unsigned short*)(ws + 33554432);   // 8x2048x1024 bf16
    unsigned short* tokb = (unsigned short*)(ws + 67108864);   // 8x2048x512  bf16 = 16,777,216
    unsigned short* latb = (unsigned short*)(ws + 83886080);   // 8x1024x512  bf16 =  8,388,608
    unsigned short* rlat = (unsigned short*)(ws + 92274688);   //  8,388,608
    unsigned short* rtok = (unsigned short*)(ws + 100663296);  // 16,777,216
    unsigned short* vlT  = (unsigned short*)(ws + 117440512);  // 8x512x1024 =  8,388,608
    unsigned short* vtT  = (unsigned short*)(ws + 125829120);  // 8x512x2048 = 16,777,216
    unsigned short* wpb  = (unsigned short*)(ws + 142606336);  // 512x1280   =  1,310,720
    unsigned short* wlb  = (unsigned short*)(ws + 143917056);  // 512x512 x4 =  2,097,152
    unsigned short* wtb  = (unsigned short*)(ws + 144441344);
    unsigned short* wvlb = (unsigned short*)(ws + 144965632);
    unsigned short* wvtb = (unsigned short*)(ws + 145489920);  // end 146,014,208
    // tokens-as-bf16 scratch lives in the concat region of d_out (overwritten later)
    unsigned short* tknb = (unsigned short*)(out + 12582912);  // 41,943,040 B <= 50,331,648 B

    // 1) all conversions + conv weight pack in one launch
    prep_all<<<2048, 256, 0, stream>>>(
        (const float4*)tokens, (const float4*)latents,
        (const float4*)W_lat, (const float4*)W_tok,
        (const float4*)W_vlat, (const float4*)W_vtok, conv_w,
        (ushort4*)tknb, (ushort4*)latb,
        (ushort4*)wlb, (ushort4*)wtb, (ushort4*)wvlb, (ushort4*)wvtb,
        (unsigned int*)wpb);

    // 2) conv-as-GEMM: tok_bf[m=16384][512], +bias
    mm_nt<1, 1><<<dim3(4, 128, 1), 256, 0, stream>>>(
        tknb, wpb, 0, 0, 1280, 1280, 1280,
        tokb, 0, nullptr, 0, nullptr, 0, conv_b, 0, 512, 1.f);

    // 3) projections (batches folded into M)
    mm_nt<0, 0><<<dim3(4, 64, 1), 256, 0, stream>>>(
        latb, wlb, 0, 0, 512, 512, 512, rlat, 0, nullptr, 0, nullptr, 0, nullptr, 0, 512, 1.f);
    mm_nt<0, 0><<<dim3(4, 128, 1), 256, 0, stream>>>(
        tokb, wtb, 0, 0, 512, 512, 512, rtok, 0, nullptr, 0, nullptr, 0, nullptr, 0, 512, 1.f);
    // V projections computed transposed: VT[e, l] = sum_d W[e,d] X[l,d]
    mm_nt<0, 0><<<dim3(8, 4, 8), 256, 0, stream>>>(
        wvlb, latb, 0, 524288, 512, 512, 512, vlT, 524288, nullptr, 0, nullptr, 0, nullptr, 0, 1024, 1.f);
    mm_nt<0, 0><<<dim3(16, 4, 8), 256, 0, stream>>>(
        wvtb, tokb, 0, 1048576, 512, 512, 512, vtT, 1048576, nullptr, 0, nullptr, 0, nullptr, 0, 2048, 1.f);

    // 4) score matrices S = scale * Rlat Rtok^T  and its transpose
    mm_nt<0, 0><<<dim3(16, 8, 8), 256, 0, stream>>>(
        rlat, rtok, 524288, 1048576, 512, 512, 512, S, 2097152, nullptr, 0, nullptr, 0, nullptr, 0, 2048, SCALEF);
    mm_nt<0, 0><<<dim3(8, 16, 8), 256, 0, stream>>>(
        rtok, rlat, 1048576, 524288, 512, 512, 512, ST, 2097152, nullptr, 0, nullptr, 0, nullptr, 0, 1024, SCALEF);

    // 5) softmax in place (row-wise on S; row-wise on ST == column-wise on S)
    rowsoftmax<2048><<<8192, 256, 0, stream>>>(S);
    rowsoftmax<1024><<<16384, 256, 0, stream>>>(ST);

    // 6) delta GEMMs with fused residual + dual write (own region + concat region)
    mm_nt<0, 2><<<dim3(4, 8, 8), 256, 0, stream>>>(
        S, vtT, 2097152, 1048576, 2048, 2048, 2048,
        nullptr, 0, out, 524288, out + 12582912, 1572864, latents, 524288, 512, 1.f);
    mm_nt<0, 3><<<dim3(4, 16, 8), 256, 0, stream>>>(
        ST, vlT, 2097152, 524288, 1024, 1024, 1024,
        nullptr, 0, out + 4194304, 1048576, out + 12582912 + 524288, 1572864, tokb, 1048576, 512, 1.f);
}

// Round 4
// 258.576 us; speedup vs baseline: 21.3376x; 1.0895x over previous
//
#include <hip/hip_runtime.h>
#include <math.h>

#define SCALEF 0.044194173824159216f   // 1/sqrt(512)

typedef __attribute__((ext_vector_type(8))) short bf16x8;
typedef __attribute__((ext_vector_type(4))) float f32x4;

static __device__ __forceinline__ unsigned short f2bf(float f) {
    union { float f; unsigned int i; } v; v.f = f;
    return (unsigned short)((v.i + 0x7fffu + ((v.i >> 16) & 1u)) >> 16);
}
static __device__ __forceinline__ float bf2f(unsigned short h) {
    union { unsigned int i; float f; } v; v.i = ((unsigned int)h) << 16;
    return v.f;
}
static __device__ __forceinline__ void gload16(const void* g, void* l) {
    __builtin_amdgcn_global_load_lds(
        (const __attribute__((address_space(1))) unsigned int*)g,
        (__attribute__((address_space(3))) unsigned int*)l, 16, 0, 0);
}

// ---------------- tokens f32 -> bf16, branch-free, 5 independent loads/thread
__global__ __launch_bounds__(256) void cvt_tokens(const float4* __restrict__ s,
                                                  ushort4* __restrict__ d) {
    long t = blockIdx.x * 256L + threadIdx.x;       // grid 4096 -> 1,048,576 threads
    #pragma unroll
    for (int k = 0; k < 5; ++k) {
        long i = t + k * 1048576L;
        float4 f = s[i];
        ushort4 u; u.x = f2bf(f.x); u.y = f2bf(f.y); u.z = f2bf(f.z); u.w = f2bf(f.w);
        d[i] = u;
    }
}

// ---------------- rest of prep: latents + 4 weights + conv pack ----------------
// unit layout (grid-stride over 1,638,400 units):
//   [0, 1048576)   latents f32x4 -> bf16x4
//   [.., +65536)x4 W_lat/W_tok/W_vlat/W_vtok
//   [.., +327680)  conv pack u32: wp[e][k*128+c2] = {cw[e][2c2][k], cw[e][2c2+1][k]}
__global__ __launch_bounds__(256) void prep_rest(
    const float4* __restrict__ latents,
    const float4* __restrict__ wl, const float4* __restrict__ wt,
    const float4* __restrict__ wvl, const float4* __restrict__ wvt,
    const float* __restrict__ cw,
    ushort4* __restrict__ latb,
    ushort4* __restrict__ wlb, ushort4* __restrict__ wtb,
    ushort4* __restrict__ wvlb, ushort4* __restrict__ wvtb,
    unsigned int* __restrict__ wpb)
{
    const long NLAT = 1048576, NW = 65536, NCV = 327680;
    for (long i = blockIdx.x * 256L + threadIdx.x; i < NLAT + 4 * NW + NCV;
         i += gridDim.x * 256L) {
        long r = i;
        const float4* s = nullptr; ushort4* d = nullptr;
        if (r < NLAT) { s = latents; d = latb; }
        else if ((r -= NLAT) < NW) { s = wl; d = wlb; }
        else if ((r -= NW) < NW) { s = wt; d = wtb; }
        else if ((r -= NW) < NW) { s = wvl; d = wvlb; }
        else if ((r -= NW) < NW) { s = wvt; d = wvtb; }
        else {
            r -= NW;  // conv unit
            long e = r / 640, rr = r % 640, k = rr >> 7, c2 = rr & 127;
            unsigned int lo = f2bf(cw[e * 1280 + (2 * c2) * 5 + k]);
            unsigned int hi = f2bf(cw[e * 1280 + (2 * c2 + 1) * 5 + k]);
            wpb[r] = lo | (hi << 16);
            continue;
        }
        float4 f = s[r];
        ushort4 u; u.x = f2bf(f.x); u.y = f2bf(f.y); u.z = f2bf(f.z); u.w = f2bf(f.w);
        d[r] = u;
    }
}

// ---------------- bf16 transpose: ST[b][s][l] = S[b][l][s] ----------------
// 64x64 tiles via LDS [64][66] (u32-aligned rows, conflict-free both phases)
__global__ __launch_bounds__(256) void transpose_bf(const unsigned short* __restrict__ S,
                                                    unsigned short* __restrict__ ST) {
    __shared__ unsigned short tl[64][66];
    const int b = blockIdx.z, r0 = blockIdx.y << 6, c0 = blockIdx.x << 6;
    const unsigned short* Sb = S + ((long)b << 21);
    unsigned short* Tb = ST + ((long)b << 21);
    const int t32 = threadIdx.x & 31, trow = threadIdx.x >> 5;
    #pragma unroll
    for (int i = 0; i < 8; ++i) {
        int r = trow + i * 8;
        unsigned int v = *(const unsigned int*)&Sb[(long)(r0 + r) * 2048 + c0 + t32 * 2];
        *(unsigned int*)&tl[r][t32 * 2] = v;
    }
    __syncthreads();
    #pragma unroll
    for (int i = 0; i < 8; ++i) {
        int c = trow + i * 8;
        unsigned int lo = tl[t32 * 2][c], hi = tl[t32 * 2 + 1][c];
        *(unsigned int*)&Tb[(long)(c0 + c) * 1024 + r0 + t32 * 2] = lo | (hi << 16);
    }
}

// ---------------- in-place row softmax (bf16), 1/sum folded in ----------------
template<int RL>
__global__ __launch_bounds__(256) void rowsoftmax(unsigned short* __restrict__ S) {
    constexpr int U = RL / 512;                 // u32 words per thread
    long row = blockIdx.x;
    unsigned int* p = (unsigned int*)(S + row * (long)RL);
    const int t = threadIdx.x, lane = t & 63, wid = t >> 6;
    unsigned int u[U];
    float v[2 * U];
    #pragma unroll
    for (int i = 0; i < U; ++i) u[i] = p[t + (i << 8)];
    #pragma unroll
    for (int i = 0; i < U; ++i) {
        v[2 * i]     = bf2f((unsigned short)(u[i] & 0xffffu));
        v[2 * i + 1] = bf2f((unsigned short)(u[i] >> 16));
    }
    float m = -INFINITY;
    #pragma unroll
    for (int i = 0; i < 2 * U; ++i) m = fmaxf(m, v[i]);
    #pragma unroll
    for (int k = 1; k < 64; k <<= 1) m = fmaxf(m, __shfl_xor(m, k));
    __shared__ float redm[4], reds[4];
    if (lane == 0) redm[wid] = m;
    __syncthreads();
    m = fmaxf(fmaxf(redm[0], redm[1]), fmaxf(redm[2], redm[3]));
    float s = 0.f, e[2 * U];
    #pragma unroll
    for (int i = 0; i < 2 * U; ++i) { e[i] = __expf(v[i] - m); s += e[i]; }
    #pragma unroll
    for (int k = 1; k < 64; k <<= 1) s += __shfl_xor(s, k);
    if (lane == 0) reds[wid] = s;
    __syncthreads();
    s = reds[0] + reds[1] + reds[2] + reds[3];
    float inv = 1.f / s;
    #pragma unroll
    for (int i = 0; i < U; ++i) {
        unsigned int lo = f2bf(e[2 * i] * inv);
        unsigned int hi = f2bf(e[2 * i + 1] * inv);
        p[t + (i << 8)] = lo | (hi << 16);
    }
}

// ---------------- MFMA NT GEMM: C[m,n] = sum_k A[m,k] * B[n,k] ----------------
// 128x128 tile, BK=32, 4 waves (2x2 of 64x64), 16x16x32 bf16 MFMA.
// Double-buffered LDS with prefetch + counted vmcnt (never full drain mid-loop).
// 16B-granule XOR swizzle applied on the GLOBAL source (dest stays linear) and
// undone on the ds_read side.
// AMODE: 0 = row m at A + m*lda.  1 = conv addressing into raw tokens (bf16).
// EPI:   0 = bf16 out (Cb) * scale
//        1 = +bias(f32, basep) then bf16 out (Cb)
//        2 = f32 base (basep) + acc -> C0 and C1
//        3 = bf16 base (basep) + acc -> C0 and C1
template<int AMODE, int EPI>
__global__ __launch_bounds__(256) void mm_nt(
    const unsigned short* __restrict__ A, const unsigned short* __restrict__ B,
    long bsA, long bsB, int lda, int ldb, int K,
    unsigned short* __restrict__ Cb, long bsCb,
    float* __restrict__ C0, long bsC0, float* __restrict__ C1, long bsC1,
    const void* __restrict__ basep, long bsBase, int ldc, float scale)
{
    __shared__ unsigned short sm[16384];        // 32KB: 2 bufs x (A 8KB + B 8KB)
    const int t = threadIdx.x, lane = t & 63, wid = t >> 6;
    const int z = blockIdx.z;
    const int m0 = blockIdx.y << 7, n0 = blockIdx.x << 7;
    const unsigned short* Ab = A + (long)z * bsA;
    const unsigned short* Bb = B + (long)z * bsB;

    const int rA0 = wid * 16 + (lane >> 2);
    const int rA1 = rA0 + 64;
    const int cs0 = (lane & 3) ^ ((rA0 >> 1) & 3);
    const int cs1 = (lane & 3) ^ ((rA1 >> 1) & 3);

    long aoff0, aoff1;
    if (AMODE == 0) {
        aoff0 = (long)(m0 + rA0) * lda + cs0 * 8;
        aoff1 = (long)(m0 + rA1) * lda + cs1 * 8;
    } else {
        int ma = m0 + rA0, mb = m0 + rA1;
        aoff0 = (long)(ma >> 11) * 2621440 + (long)(ma & 2047) * 1280 + cs0 * 8;
        aoff1 = (long)(mb >> 11) * 2621440 + (long)(mb & 2047) * 1280 + cs1 * 8;
    }
    const long boff0 = (long)(n0 + rA0) * ldb + cs0 * 8;
    const long boff1 = (long)(n0 + rA1) * ldb + cs1 * 8;

    char* smc = (char*)sm;
    const int dA0 = (wid << 10), dA1 = ((wid + 4) << 10);
    const int dB0 = 8192 + (wid << 10), dB1 = 8192 + ((wid + 4) << 10);

    const int wr = wid >> 1, wc = wid & 1;
    const int l15 = lane & 15, cslot = lane >> 4;
    int offA[4], offB[4];
    #pragma unroll
    for (int i = 0; i < 4; ++i) {
        int r = wr * 64 + i * 16 + l15;
        offA[i] = r * 64 + ((cslot ^ ((r >> 1) & 3)) << 4);
        int rb = wc * 64 + i * 16 + l15;
        offB[i] = 8192 + rb * 64 + ((cslot ^ ((rb >> 1) & 3)) << 4);
    }

    f32x4 acc[4][4];
    #pragma unroll
    for (int i = 0; i < 4; ++i)
        #pragma unroll
        for (int j = 0; j < 4; ++j)
            acc[i][j] = (f32x4)(0.f);

#define STAGE(p, ktv) do {                                   \
        int kb_ = (ktv);                                     \
        int bo_ = (p) * 16384;                               \
        gload16(Ab + aoff0 + kb_, smc + bo_ + dA0);          \
        gload16(Ab + aoff1 + kb_, smc + bo_ + dA1);          \
        gload16(Bb + boff0 + kb_, smc + bo_ + dB0);          \
        gload16(Bb + boff1 + kb_, smc + bo_ + dB1);          \
    } while (0)

    const int nt = K >> 5;
    STAGE(0, 0);
    int cur = 0;
    for (int it = 0; it < nt; ++it) {
        if (it + 1 < nt) {
            STAGE(cur ^ 1, (it + 1) << 5);
            asm volatile("s_waitcnt vmcnt(4)" ::: "memory");
        } else {
            asm volatile("s_waitcnt vmcnt(0)" ::: "memory");
        }
        __builtin_amdgcn_s_barrier();
        const char* base = smc + cur * 16384;
        bf16x8 af[4], bfr[4];
        #pragma unroll
        for (int i = 0; i < 4; ++i) af[i]  = *(const bf16x8*)(base + offA[i]);
        #pragma unroll
        for (int i = 0; i < 4; ++i) bfr[i] = *(const bf16x8*)(base + offB[i]);
        #pragma unroll
        for (int i = 0; i < 4; ++i)
            #pragma unroll
            for (int j = 0; j < 4; ++j)
                acc[i][j] = __builtin_amdgcn_mfma_f32_16x16x32_bf16(af[i], bfr[j], acc[i][j], 0, 0, 0);
        asm volatile("s_waitcnt lgkmcnt(0)" ::: "memory");
        __builtin_amdgcn_s_barrier();
        cur ^= 1;
    }
#undef STAGE

    // epilogue: C/D frag layout col=lane&15, row=(lane>>4)*4+q  [m89-verified]
    const int colb = n0 + wc * 64 + l15;
    const int rowb = m0 + wr * 64 + cslot * 4;
    #pragma unroll
    for (int i = 0; i < 4; ++i) {
        #pragma unroll
        for (int j = 0; j < 4; ++j) {
            int n = colb + j * 16;
            #pragma unroll
            for (int q = 0; q < 4; ++q) {
                int m = rowb + i * 16 + q;
                float v = acc[i][j][q];
                if (EPI == 0) {
                    Cb[(long)z * bsCb + (long)m * ldc + n] = f2bf(v * scale);
                } else if (EPI == 1) {
                    v += ((const float*)basep)[n];
                    Cb[(long)m * ldc + n] = f2bf(v);
                } else if (EPI == 2) {
                    float bv = ((const float*)basep)[(long)z * bsBase + (long)m * ldc + n];
                    float o = bv + v;
                    C0[(long)z * bsC0 + (long)m * ldc + n] = o;
                    C1[(long)z * bsC1 + (long)m * ldc + n] = o;
                } else {
                    float bv = bf2f(((const unsigned short*)basep)[(long)z * bsBase + (long)m * ldc + n]);
                    float o = bv + v;
                    C0[(long)z * bsC0 + (long)m * ldc + n] = o;
                    C1[(long)z * bsC1 + (long)m * ldc + n] = o;
                }
            }
        }
    }
}

extern "C" void kernel_launch(void* const* d_in, const int* in_sizes, int n_in,
                              void* d_out, int out_size, void* d_ws, size_t ws_size,
                              hipStream_t stream)
{
    const float* latents = (const float*)d_in[0];
    const float* tokens  = (const float*)d_in[1];
    const float* W_lat   = (const float*)d_in[2];
    const float* W_tok   = (const float*)d_in[3];
    const float* W_vlat  = (const float*)d_in[4];
    const float* W_vtok  = (const float*)d_in[5];
    const float* conv_w  = (const float*)d_in[6];
    const float* conv_b  = (const float*)d_in[7];
    float* out = (float*)d_out;
    char* ws = (char*)d_ws;

    // workspace layout (bytes)
    unsigned short* S    = (unsigned short*)(ws);              // 8x1024x2048 bf16 = 33,554,432
    unsigned short* ST   = (unsigned short*)(ws + 33554432);   // 8x2048x1024 bf16
    unsigned short* tokb = (unsigned short*)(ws + 67108864);   // 8x2048x512  bf16 = 16,777,216
    unsigned short* latb = (unsigned short*)(ws + 83886080);   // 8x1024x512  bf16 =  8,388,608
    unsigned short* rlat = (unsigned short*)(ws + 92274688);   //  8,388,608
    unsigned short* rtok = (unsigned short*)(ws + 100663296);  // 16,777,216
    unsigned short* vlT  = (unsigned short*)(ws + 117440512);  // 8x512x1024 =  8,388,608
    unsigned short* vtT  = (unsigned short*)(ws + 125829120);  // 8x512x2048 = 16,777,216
    unsigned short* wpb  = (unsigned short*)(ws + 142606336);  // 512x1280   =  1,310,720
    unsigned short* wlb  = (unsigned short*)(ws + 143917056);  // 512x512 x4 =  2,097,152
    unsigned short* wtb  = (unsigned short*)(ws + 144441344);
    unsigned short* wvlb = (unsigned short*)(ws + 144965632);
    unsigned short* wvtb = (unsigned short*)(ws + 145489920);  // end 146,014,208
    // tokens-as-bf16 scratch lives in the concat region of d_out (overwritten later)
    unsigned short* tknb = (unsigned short*)(out + 12582912);  // 41,943,040 B <= 50,331,648 B

    // 1) conversions + conv weight pack (branch-free bulk stream + small rest)
    cvt_tokens<<<4096, 256, 0, stream>>>((const float4*)tokens, (ushort4*)tknb);
    prep_rest<<<1024, 256, 0, stream>>>(
        (const float4*)latents,
        (const float4*)W_lat, (const float4*)W_tok,
        (const float4*)W_vlat, (const float4*)W_vtok, conv_w,
        (ushort4*)latb,
        (ushort4*)wlb, (ushort4*)wtb, (ushort4*)wvlb, (ushort4*)wvtb,
        (unsigned int*)wpb);

    // 2) conv-as-GEMM: tok_bf[m=16384][512], +bias
    mm_nt<1, 1><<<dim3(4, 128, 1), 256, 0, stream>>>(
        tknb, wpb, 0, 0, 1280, 1280, 1280,
        tokb, 0, nullptr, 0, nullptr, 0, conv_b, 0, 512, 1.f);

    // 3) projections (batches folded into M)
    mm_nt<0, 0><<<dim3(4, 64, 1), 256, 0, stream>>>(
        latb, wlb, 0, 0, 512, 512, 512, rlat, 0, nullptr, 0, nullptr, 0, nullptr, 0, 512, 1.f);
    mm_nt<0, 0><<<dim3(4, 128, 1), 256, 0, stream>>>(
        tokb, wtb, 0, 0, 512, 512, 512, rtok, 0, nullptr, 0, nullptr, 0, nullptr, 0, 512, 1.f);
    // V projections computed transposed: VT[e, l] = sum_d W[e,d] X[l,d]
    mm_nt<0, 0><<<dim3(8, 4, 8), 256, 0, stream>>>(
        wvlb, latb, 0, 524288, 512, 512, 512, vlT, 524288, nullptr, 0, nullptr, 0, nullptr, 0, 1024, 1.f);
    mm_nt<0, 0><<<dim3(16, 4, 8), 256, 0, stream>>>(
        wvtb, tokb, 0, 1048576, 512, 512, 512, vtT, 1048576, nullptr, 0, nullptr, 0, nullptr, 0, 2048, 1.f);

    // 4) score matrix S = scale * Rlat Rtok^T; ST by transpose (same bf16 values)
    mm_nt<0, 0><<<dim3(16, 8, 8), 256, 0, stream>>>(
        rlat, rtok, 524288, 1048576, 512, 512, 512, S, 2097152, nullptr, 0, nullptr, 0, nullptr, 0, 2048, SCALEF);
    transpose_bf<<<dim3(32, 16, 8), 256, 0, stream>>>(S, ST);

    // 5) softmax in place (row-wise on S; row-wise on ST == column-wise on S)
    rowsoftmax<2048><<<8192, 256, 0, stream>>>(S);
    rowsoftmax<1024><<<16384, 256, 0, stream>>>(ST);

    // 6) delta GEMMs with fused residual + dual write (own region + concat region)
    mm_nt<0, 2><<<dim3(4, 8, 8), 256, 0, stream>>>(
        S, vtT, 2097152, 1048576, 2048, 2048, 2048,
        nullptr, 0, out, 524288, out + 12582912, 1572864, latents, 524288, 512, 1.f);
    mm_nt<0, 3><<<dim3(4, 16, 8), 256, 0, stream>>>(
        ST, vlT, 2097152, 524288, 1024, 1024, 1024,
        nullptr, 0, out + 4194304, 1048576, out + 12582912 + 524288, 1572864, tokb, 1048576, 512, 1.f);
}

// Round 5
// 253.272 us; speedup vs baseline: 21.7844x; 1.0209x over previous
//
#include <hip/hip_runtime.h>
#include <math.h>

#define SCALEF 0.044194173824159216f   // 1/sqrt(512)

typedef __attribute__((ext_vector_type(8))) short bf16x8;
typedef __attribute__((ext_vector_type(4))) float f32x4;

static __device__ __forceinline__ unsigned short f2bf(float f) {
    union { float f; unsigned int i; } v; v.f = f;
    return (unsigned short)((v.i + 0x7fffu + ((v.i >> 16) & 1u)) >> 16);
}
static __device__ __forceinline__ float bf2f(unsigned short h) {
    union { unsigned int i; float f; } v; v.i = ((unsigned int)h) << 16;
    return v.f;
}
static __device__ __forceinline__ void gload16(const void* g, void* l) {
    __builtin_amdgcn_global_load_lds(
        (const __attribute__((address_space(1))) unsigned int*)g,
        (__attribute__((address_space(3))) unsigned int*)l, 16, 0, 0);
}

// ---- tokens + latents f32 -> bf16, branch-free, 6 independent loads/thread --
__global__ __launch_bounds__(256) void cvt_tl(const float4* __restrict__ tok,
                                              const float4* __restrict__ lat,
                                              ushort4* __restrict__ tokd,
                                              ushort4* __restrict__ latd) {
    long t = blockIdx.x * 256L + threadIdx.x;       // grid 4096 -> 1,048,576 threads
    #pragma unroll
    for (int k = 0; k < 5; ++k) {
        long i = t + k * 1048576L;
        float4 f = tok[i];
        ushort4 u; u.x = f2bf(f.x); u.y = f2bf(f.y); u.z = f2bf(f.z); u.w = f2bf(f.w);
        tokd[i] = u;
    }
    {
        float4 f = lat[t];
        ushort4 u; u.x = f2bf(f.x); u.y = f2bf(f.y); u.z = f2bf(f.z); u.w = f2bf(f.w);
        latd[t] = u;
    }
}

// ---- rest of prep: 4 weights + conv pack ----
// unit layout (grid-stride over 589,824 units):
//   [0, 65536)x4   W_lat/W_tok/W_vlat/W_vtok  f32x4 -> bf16x4
//   [.., +327680)  conv pack u32: wp[e][k*128+c2] = {cw[e][2c2][k], cw[e][2c2+1][k]}
__global__ __launch_bounds__(256) void prep_rest(
    const float4* __restrict__ wl, const float4* __restrict__ wt,
    const float4* __restrict__ wvl, const float4* __restrict__ wvt,
    const float* __restrict__ cw,
    ushort4* __restrict__ wlb, ushort4* __restrict__ wtb,
    ushort4* __restrict__ wvlb, ushort4* __restrict__ wvtb,
    unsigned int* __restrict__ wpb)
{
    const long NW = 65536, NCV = 327680;
    for (long i = blockIdx.x * 256L + threadIdx.x; i < 4 * NW + NCV;
         i += gridDim.x * 256L) {
        long r = i;
        const float4* s = nullptr; ushort4* d = nullptr;
        if (r < NW) { s = wl; d = wlb; }
        else if ((r -= NW) < NW) { s = wt; d = wtb; }
        else if ((r -= NW) < NW) { s = wvl; d = wvlb; }
        else if ((r -= NW) < NW) { s = wvt; d = wvtb; }
        else {
            r -= NW;  // conv unit
            long e = r / 640, rr = r % 640, k = rr >> 7, c2 = rr & 127;
            unsigned int lo = f2bf(cw[e * 1280 + (2 * c2) * 5 + k]);
            unsigned int hi = f2bf(cw[e * 1280 + (2 * c2 + 1) * 5 + k]);
            wpb[r] = lo | (hi << 16);
            continue;
        }
        float4 f = s[r];
        ushort4 u; u.x = f2bf(f.x); u.y = f2bf(f.y); u.z = f2bf(f.z); u.w = f2bf(f.w);
        d[r] = u;
    }
}

// ---------------- bf16 transpose: ST[b][s][l] = S[b][l][s] ----------------
// 64x64 tiles via LDS [64][66] (u32-aligned rows, conflict-free both phases)
__global__ __launch_bounds__(256) void transpose_bf(const unsigned short* __restrict__ S,
                                                    unsigned short* __restrict__ ST) {
    __shared__ unsigned short tl[64][66];
    const int b = blockIdx.z, r0 = blockIdx.y << 6, c0 = blockIdx.x << 6;
    const unsigned short* Sb = S + ((long)b << 21);
    unsigned short* Tb = ST + ((long)b << 21);
    const int t32 = threadIdx.x & 31, trow = threadIdx.x >> 5;
    #pragma unroll
    for (int i = 0; i < 8; ++i) {
        int r = trow + i * 8;
        unsigned int v = *(const unsigned int*)&Sb[(long)(r0 + r) * 2048 + c0 + t32 * 2];
        *(unsigned int*)&tl[r][t32 * 2] = v;
    }
    __syncthreads();
    #pragma unroll
    for (int i = 0; i < 8; ++i) {
        int c = trow + i * 8;
        unsigned int lo = tl[t32 * 2][c], hi = tl[t32 * 2 + 1][c];
        *(unsigned int*)&Tb[(long)(c0 + c) * 1024 + r0 + t32 * 2] = lo | (hi << 16);
    }
}

// ------------- in-place row softmax body (bf16), 1/sum folded in -------------
template<int RL>
static __device__ __forceinline__ void sm_body(unsigned short* __restrict__ rowp,
                                               float* __restrict__ redm,
                                               float* __restrict__ reds) {
    constexpr int U = RL / 512;                 // u32 words per thread
    unsigned int* p = (unsigned int*)rowp;
    const int t = threadIdx.x, lane = t & 63, wid = t >> 6;
    unsigned int u[U];
    float v[2 * U];
    #pragma unroll
    for (int i = 0; i < U; ++i) u[i] = p[t + (i << 8)];
    #pragma unroll
    for (int i = 0; i < U; ++i) {
        v[2 * i]     = bf2f((unsigned short)(u[i] & 0xffffu));
        v[2 * i + 1] = bf2f((unsigned short)(u[i] >> 16));
    }
    float m = -INFINITY;
    #pragma unroll
    for (int i = 0; i < 2 * U; ++i) m = fmaxf(m, v[i]);
    #pragma unroll
    for (int k = 1; k < 64; k <<= 1) m = fmaxf(m, __shfl_xor(m, k));
    if (lane == 0) redm[wid] = m;
    __syncthreads();
    m = fmaxf(fmaxf(redm[0], redm[1]), fmaxf(redm[2], redm[3]));
    float s = 0.f, e[2 * U];
    #pragma unroll
    for (int i = 0; i < 2 * U; ++i) { e[i] = __expf(v[i] - m); s += e[i]; }
    #pragma unroll
    for (int k = 1; k < 64; k <<= 1) s += __shfl_xor(s, k);
    if (lane == 0) reds[wid] = s;
    __syncthreads();
    s = reds[0] + reds[1] + reds[2] + reds[3];
    float inv = 1.f / s;
    #pragma unroll
    for (int i = 0; i < U; ++i) {
        unsigned int lo = f2bf(e[2 * i] * inv);
        unsigned int hi = f2bf(e[2 * i + 1] * inv);
        p[t + (i << 8)] = lo | (hi << 16);
    }
}

// one launch: blocks [0,8192) do S rows (len 2048), [8192, 24576) do ST rows (len 1024)
__global__ __launch_bounds__(256) void softmax_both(unsigned short* __restrict__ S,
                                                    unsigned short* __restrict__ ST) {
    __shared__ float redm[4], reds[4];
    long b = blockIdx.x;
    if (b < 8192) sm_body<2048>(S + b * 2048L, redm, reds);
    else          sm_body<1024>(ST + (b - 8192) * 1024L, redm, reds);
}

// ---------------- MFMA NT GEMM: C[m,n] = sum_k A[m,k] * B[n,k] ----------------
// 128x128 tile, BK=32, 4 waves (2x2 of 64x64), 16x16x32 bf16 MFMA.
// Triple-buffered LDS, depth-2 prefetch: tiles it+1 and it+2 are in flight while
// computing tile it; counted s_waitcnt vmcnt(8) (tail 4 -> 0), raw s_barrier.
// 16B-granule XOR swizzle applied on the GLOBAL source (dest stays linear) and
// undone on the ds_read side.
// AMODE: 0 = row m at A + m*lda.  1 = conv addressing into raw tokens (bf16).
// EPI:   0 = bf16 out (Cb) * scale
//        1 = +bias(f32, basep) then bf16 out (Cb)
//        2 = f32 base (basep) + acc -> C0 and C1
//        3 = bf16 base (basep) + acc -> C0 and C1
template<int AMODE, int EPI>
__global__ __launch_bounds__(256) void mm_nt(
    const unsigned short* __restrict__ A, const unsigned short* __restrict__ B,
    long bsA, long bsB, int lda, int ldb, int K,
    unsigned short* __restrict__ Cb, long bsCb,
    float* __restrict__ C0, long bsC0, float* __restrict__ C1, long bsC1,
    const void* __restrict__ basep, long bsBase, int ldc, float scale)
{
    __shared__ unsigned short sm[24576];        // 48KB: 3 bufs x (A 8KB + B 8KB)
    const int t = threadIdx.x, lane = t & 63, wid = t >> 6;
    const int z = blockIdx.z;
    const int m0 = blockIdx.y << 7, n0 = blockIdx.x << 7;
    const unsigned short* Ab = A + (long)z * bsA;
    const unsigned short* Bb = B + (long)z * bsB;

    const int rA0 = wid * 16 + (lane >> 2);
    const int rA1 = rA0 + 64;
    const int cs0 = (lane & 3) ^ ((rA0 >> 1) & 3);
    const int cs1 = (lane & 3) ^ ((rA1 >> 1) & 3);

    long aoff0, aoff1;
    if (AMODE == 0) {
        aoff0 = (long)(m0 + rA0) * lda + cs0 * 8;
        aoff1 = (long)(m0 + rA1) * lda + cs1 * 8;
    } else {
        int ma = m0 + rA0, mb = m0 + rA1;
        aoff0 = (long)(ma >> 11) * 2621440 + (long)(ma & 2047) * 1280 + cs0 * 8;
        aoff1 = (long)(mb >> 11) * 2621440 + (long)(mb & 2047) * 1280 + cs1 * 8;
    }
    const long boff0 = (long)(n0 + rA0) * ldb + cs0 * 8;
    const long boff1 = (long)(n0 + rA1) * ldb + cs1 * 8;

    char* smc = (char*)sm;
    const int dA0 = (wid << 10), dA1 = ((wid + 4) << 10);
    const int dB0 = 8192 + (wid << 10), dB1 = 8192 + ((wid + 4) << 10);

    const int wr = wid >> 1, wc = wid & 1;
    const int l15 = lane & 15, cslot = lane >> 4;
    int offA[4], offB[4];
    #pragma unroll
    for (int i = 0; i < 4; ++i) {
        int r = wr * 64 + i * 16 + l15;
        offA[i] = r * 64 + ((cslot ^ ((r >> 1) & 3)) << 4);
        int rb = wc * 64 + i * 16 + l15;
        offB[i] = 8192 + rb * 64 + ((cslot ^ ((rb >> 1) & 3)) << 4);
    }

    f32x4 acc[4][4];
    #pragma unroll
    for (int i = 0; i < 4; ++i)
        #pragma unroll
        for (int j = 0; j < 4; ++j)
            acc[i][j] = (f32x4)(0.f);

#define STAGE(p, ktv) do {                                   \
        int kb_ = (ktv);                                     \
        int bo_ = (p) * 16384;                               \
        gload16(Ab + aoff0 + kb_, smc + bo_ + dA0);          \
        gload16(Ab + aoff1 + kb_, smc + bo_ + dA1);          \
        gload16(Bb + boff0 + kb_, smc + bo_ + dB0);          \
        gload16(Bb + boff1 + kb_, smc + bo_ + dB1);          \
    } while (0)

    const int nt = K >> 5;                      // always >= 2 here
    STAGE(0, 0);
    STAGE(1, 32);
    int cur = 0;
    for (int it = 0; it < nt; ++it) {
        if (it + 2 < nt) {
            int nx = (cur >= 1) ? cur - 1 : 2;  // (cur+2)%3
            STAGE(nx, (it + 2) << 5);
            asm volatile("s_waitcnt vmcnt(8)" ::: "memory");
        } else if (it + 1 < nt) {
            asm volatile("s_waitcnt vmcnt(4)" ::: "memory");
        } else {
            asm volatile("s_waitcnt vmcnt(0)" ::: "memory");
        }
        __builtin_amdgcn_s_barrier();
        const char* base = smc + cur * 16384;
        bf16x8 af[4], bfr[4];
        #pragma unroll
        for (int i = 0; i < 4; ++i) af[i]  = *(const bf16x8*)(base + offA[i]);
        #pragma unroll
        for (int i = 0; i < 4; ++i) bfr[i] = *(const bf16x8*)(base + offB[i]);
        #pragma unroll
        for (int i = 0; i < 4; ++i)
            #pragma unroll
            for (int j = 0; j < 4; ++j)
                acc[i][j] = __builtin_amdgcn_mfma_f32_16x16x32_bf16(af[i], bfr[j], acc[i][j], 0, 0, 0);
        asm volatile("s_waitcnt lgkmcnt(0)" ::: "memory");
        __builtin_amdgcn_s_barrier();
        cur = (cur + 1 == 3) ? 0 : cur + 1;
    }
#undef STAGE

    // epilogue: C/D frag layout col=lane&15, row=(lane>>4)*4+q  [m89-verified]
    const int colb = n0 + wc * 64 + l15;
    const int rowb = m0 + wr * 64 + cslot * 4;
    #pragma unroll
    for (int i = 0; i < 4; ++i) {
        #pragma unroll
        for (int j = 0; j < 4; ++j) {
            int n = colb + j * 16;
            #pragma unroll
            for (int q = 0; q < 4; ++q) {
                int m = rowb + i * 16 + q;
                float v = acc[i][j][q];
                if (EPI == 0) {
                    Cb[(long)z * bsCb + (long)m * ldc + n] = f2bf(v * scale);
                } else if (EPI == 1) {
                    v += ((const float*)basep)[n];
                    Cb[(long)m * ldc + n] = f2bf(v);
                } else if (EPI == 2) {
                    float bv = ((const float*)basep)[(long)z * bsBase + (long)m * ldc + n];
                    float o = bv + v;
                    C0[(long)z * bsC0 + (long)m * ldc + n] = o;
                    C1[(long)z * bsC1 + (long)m * ldc + n] = o;
                } else {
                    float bv = bf2f(((const unsigned short*)basep)[(long)z * bsBase + (long)m * ldc + n]);
                    float o = bv + v;
                    C0[(long)z * bsC0 + (long)m * ldc + n] = o;
                    C1[(long)z * bsC1 + (long)m * ldc + n] = o;
                }
            }
        }
    }
}

extern "C" void kernel_launch(void* const* d_in, const int* in_sizes, int n_in,
                              void* d_out, int out_size, void* d_ws, size_t ws_size,
                              hipStream_t stream)
{
    const float* latents = (const float*)d_in[0];
    const float* tokens  = (const float*)d_in[1];
    const float* W_lat   = (const float*)d_in[2];
    const float* W_tok   = (const float*)d_in[3];
    const float* W_vlat  = (const float*)d_in[4];
    const float* W_vtok  = (const float*)d_in[5];
    const float* conv_w  = (const float*)d_in[6];
    const float* conv_b  = (const float*)d_in[7];
    float* out = (float*)d_out;
    char* ws = (char*)d_ws;

    // workspace layout (bytes)
    unsigned short* S    = (unsigned short*)(ws);              // 8x1024x2048 bf16 = 33,554,432
    unsigned short* ST   = (unsigned short*)(ws + 33554432);   // 8x2048x1024 bf16
    unsigned short* tokb = (unsigned short*)(ws + 67108864);   // 8x2048x512  bf16 = 16,777,216
    unsigned short* latb = (unsigned short*)(ws + 83886080);   // 8x1024x512  bf16 =  8,388,608
    unsigned short* rlat = (unsigned short*)(ws + 92274688);   //  8,388,608
    unsigned short* rtok = (unsigned short*)(ws + 100663296);  // 16,777,216
    unsigned short* vlT  = (unsigned short*)(ws + 117440512);  // 8x512x1024 =  8,388,608
    unsigned short* vtT  = (unsigned short*)(ws + 125829120);  // 8x512x2048 = 16,777,216
    unsigned short* wpb  = (unsigned short*)(ws + 142606336);  // 512x1280   =  1,310,720
    unsigned short* wlb  = (unsigned short*)(ws + 143917056);  // 512x512 x4 =  2,097,152
    unsigned short* wtb  = (unsigned short*)(ws + 144441344);
    unsigned short* wvlb = (unsigned short*)(ws + 144965632);
    unsigned short* wvtb = (unsigned short*)(ws + 145489920);  // end 146,014,208
    // tokens-as-bf16 scratch lives in the concat region of d_out (overwritten later)
    unsigned short* tknb = (unsigned short*)(out + 12582912);  // 41,943,040 B <= 50,331,648 B

    // 1) conversions + conv weight pack
    cvt_tl<<<4096, 256, 0, stream>>>((const float4*)tokens, (const float4*)latents,
                                     (ushort4*)tknb, (ushort4*)latb);
    prep_rest<<<512, 256, 0, stream>>>(
        (const float4*)W_lat, (const float4*)W_tok,
        (const float4*)W_vlat, (const float4*)W_vtok, conv_w,
        (ushort4*)wlb, (ushort4*)wtb, (ushort4*)wvlb, (ushort4*)wvtb,
        (unsigned int*)wpb);

    // 2) conv-as-GEMM: tok_bf[m=16384][512], +bias
    mm_nt<1, 1><<<dim3(4, 128, 1), 256, 0, stream>>>(
        tknb, wpb, 0, 0, 1280, 1280, 1280,
        tokb, 0, nullptr, 0, nullptr, 0, conv_b, 0, 512, 1.f);

    // 3) projections (batches folded into M)
    mm_nt<0, 0><<<dim3(4, 64, 1), 256, 0, stream>>>(
        latb, wlb, 0, 0, 512, 512, 512, rlat, 0, nullptr, 0, nullptr, 0, nullptr, 0, 512, 1.f);
    mm_nt<0, 0><<<dim3(4, 128, 1), 256, 0, stream>>>(
        tokb, wtb, 0, 0, 512, 512, 512, rtok, 0, nullptr, 0, nullptr, 0, nullptr, 0, 512, 1.f);
    // V projections computed transposed: VT[e, l] = sum_d W[e,d] X[l,d]
    mm_nt<0, 0><<<dim3(8, 4, 8), 256, 0, stream>>>(
        wvlb, latb, 0, 524288, 512, 512, 512, vlT, 524288, nullptr, 0, nullptr, 0, nullptr, 0, 1024, 1.f);
    mm_nt<0, 0><<<dim3(16, 4, 8), 256, 0, stream>>>(
        wvtb, tokb, 0, 1048576, 512, 512, 512, vtT, 1048576, nullptr, 0, nullptr, 0, nullptr, 0, 2048, 1.f);

    // 4) score matrix S = scale * Rlat Rtok^T; ST by transpose (same bf16 values)
    mm_nt<0, 0><<<dim3(16, 8, 8), 256, 0, stream>>>(
        rlat, rtok, 524288, 1048576, 512, 512, 512, S, 2097152, nullptr, 0, nullptr, 0, nullptr, 0, 2048, SCALEF);
    transpose_bf<<<dim3(32, 16, 8), 256, 0, stream>>>(S, ST);

    // 5) softmax in place, both matrices, one launch
    softmax_both<<<24576, 256, 0, stream>>>(S, ST);

    // 6) delta GEMMs with fused residual + dual write (own region + concat region)
    mm_nt<0, 2><<<dim3(4, 8, 8), 256, 0, stream>>>(
        S, vtT, 2097152, 1048576, 2048, 2048, 2048,
        nullptr, 0, out, 524288, out + 12582912, 1572864, latents, 524288, 512, 1.f);
    mm_nt<0, 3><<<dim3(4, 16, 8), 256, 0, stream>>>(
        ST, vlT, 2097152, 524288, 1024, 1024, 1024,
        nullptr, 0, out + 4194304, 1048576, out + 12582912 + 524288, 1572864, tokb, 1048576, 512, 1.f);
}